// Round 1
// baseline (864.364 us; speedup 1.0000x reference)
//
#include <hip/hip_runtime.h>
#include <hip/hip_bf16.h>
#include <stdint.h>

typedef __attribute__((ext_vector_type(4))) float f32x4;
typedef __attribute__((ext_vector_type(8))) short short8;

// RNE fp32 -> bf16 (inputs are finite; no NaN handling needed)
__device__ __forceinline__ unsigned short f32_to_bf16_rne(float f) {
  union { float f; unsigned int u; } v; v.f = f;
  unsigned int u = v.u;
  unsigned int r = u + 0x7fffu + ((u >> 16) & 1u);
  return (unsigned short)(r >> 16);
}

// async global->LDS, 16B per lane. LDS dest must be wave-linear (base + lane*16).
#define GLOAD16(gp, lp)                                               \
  __builtin_amdgcn_global_load_lds(                                   \
      (const __attribute__((address_space(1))) void*)(const void*)(gp), \
      (__attribute__((address_space(3))) void*)(void*)(lp), 16, 0, 0)

__global__ __launch_bounds__(256) void cvt_f32_bf16(const float* __restrict__ in,
                                                    unsigned short* __restrict__ out,
                                                    int n4) {
  int i = blockIdx.x * 256 + threadIdx.x;
  int stride = gridDim.x * 256;
  for (; i < n4; i += stride) {
    float4 v = reinterpret_cast<const float4*>(in)[i];
    ushort4 o;
    o.x = f32_to_bf16_rne(v.x);
    o.y = f32_to_bf16_rne(v.y);
    o.z = f32_to_bf16_rne(v.z);
    o.w = f32_to_bf16_rne(v.w);
    reinterpret_cast<ushort4*>(out)[i] = o;
  }
}

// Fused gate/up GEMM + SwiGLU epilogue.
// C_h[m][n] = silu(sum_k A[m][k]*Bg[n][k]) * sum_k A[m][k]*Bu[n][k]
// A: M x K bf16 row-major; Bg,Bu: N x K bf16 row-major; Hm: M x N bf16.
__global__ __launch_bounds__(256) void gemm1_swiglu(
    const unsigned short* __restrict__ A,
    const unsigned short* __restrict__ Bg,
    const unsigned short* __restrict__ Bu,
    unsigned short* __restrict__ Hm,
    int M, int N, int K) {
  __shared__ unsigned short sA[128 * 32];
  __shared__ unsigned short sBg[128 * 32];
  __shared__ unsigned short sBu[128 * 32];

  const int t = threadIdx.x;
  const int lane = t & 63;
  const int wave = t >> 6;
  const int wr = wave >> 1;  // 0..1 (M half)
  const int wc = wave & 1;   // 0..1 (N half)
  const int bm = blockIdx.x, bn = blockIdx.y;

  // staging: thread t covers row (t>>2), 16B chunk (t&3) within 64B row
  const int sr = t >> 2;
  const int sc = (t & 3) * 8;

  const unsigned short* gA  = A  + (size_t)(bm * 128 + sr) * K + sc;
  const unsigned short* gBg = Bg + (size_t)(bn * 128 + sr) * K + sc;
  const unsigned short* gBu = Bu + (size_t)(bn * 128 + sr) * K + sc;
  const size_t rowskip = (size_t)64 * K;  // pass-1: rows 64..127

  unsigned short* lA  = &sA[t * 8];
  unsigned short* lBg = &sBg[t * 8];
  unsigned short* lBu = &sBu[t * 8];

  f32x4 accg[4][4] = {};
  f32x4 accu[4][4] = {};

  const int frow = lane & 15;
  const int fkb  = (lane >> 4) * 8;

  for (int k0 = 0; k0 < K; k0 += 32) {
    GLOAD16(gA, lA);                    GLOAD16(gA + rowskip, lA + 2048);
    GLOAD16(gBg, lBg);                  GLOAD16(gBg + rowskip, lBg + 2048);
    GLOAD16(gBu, lBu);                  GLOAD16(gBu + rowskip, lBu + 2048);
    gA += 32; gBg += 32; gBu += 32;
    __syncthreads();  // compiler emits vmcnt(0) drain before barrier

    short8 af[4], bgf[4], buf_[4];
#pragma unroll
    for (int mi = 0; mi < 4; ++mi)
      af[mi] = *reinterpret_cast<const short8*>(&sA[(wr * 64 + mi * 16 + frow) * 32 + fkb]);
#pragma unroll
    for (int ni = 0; ni < 4; ++ni) {
      bgf[ni]  = *reinterpret_cast<const short8*>(&sBg[(wc * 64 + ni * 16 + frow) * 32 + fkb]);
      buf_[ni] = *reinterpret_cast<const short8*>(&sBu[(wc * 64 + ni * 16 + frow) * 32 + fkb]);
    }
#pragma unroll
    for (int mi = 0; mi < 4; ++mi)
#pragma unroll
      for (int ni = 0; ni < 4; ++ni) {
        accg[mi][ni] = __builtin_amdgcn_mfma_f32_16x16x32_bf16(af[mi], bgf[ni],  accg[mi][ni], 0, 0, 0);
        accu[mi][ni] = __builtin_amdgcn_mfma_f32_16x16x32_bf16(af[mi], buf_[ni], accu[mi][ni], 0, 0, 0);
      }
    __syncthreads();
  }

  // epilogue: C row = (lane>>4)*4 + j, col = lane&15  [m89-verified layout]
  const int r0 = bm * 128 + wr * 64 + (lane >> 4) * 4;
  const int c0 = bn * 128 + wc * 64 + frow;
#pragma unroll
  for (int mi = 0; mi < 4; ++mi)
#pragma unroll
    for (int ni = 0; ni < 4; ++ni)
#pragma unroll
      for (int j = 0; j < 4; ++j) {
        float g = accg[mi][ni][j];
        float u = accu[mi][ni][j];
        float h = g * u / (1.0f + __expf(-g));  // silu(g)*u
        Hm[(size_t)(r0 + mi * 16 + j) * N + (c0 + ni * 16)] = f32_to_bf16_rne(h);
      }
}

// y[m][n] = sum_k A[m][k] * B[n][k];  A: M x K bf16, B: N x K bf16, C: M x N fp32
__global__ __launch_bounds__(256) void gemm2_bt(
    const unsigned short* __restrict__ A,
    const unsigned short* __restrict__ B,
    float* __restrict__ C,
    int M, int N, int K) {
  __shared__ unsigned short sA[128 * 32];
  __shared__ unsigned short sB[128 * 32];

  const int t = threadIdx.x;
  const int lane = t & 63;
  const int wave = t >> 6;
  const int wr = wave >> 1;
  const int wc = wave & 1;
  const int bm = blockIdx.x, bn = blockIdx.y;

  const int sr = t >> 2;
  const int sc = (t & 3) * 8;

  const unsigned short* gA = A + (size_t)(bm * 128 + sr) * K + sc;
  const unsigned short* gB = B + (size_t)(bn * 128 + sr) * K + sc;
  const size_t rowskip = (size_t)64 * K;

  unsigned short* lA = &sA[t * 8];
  unsigned short* lB = &sB[t * 8];

  f32x4 acc[4][4] = {};

  const int frow = lane & 15;
  const int fkb  = (lane >> 4) * 8;

  for (int k0 = 0; k0 < K; k0 += 32) {
    GLOAD16(gA, lA);  GLOAD16(gA + rowskip, lA + 2048);
    GLOAD16(gB, lB);  GLOAD16(gB + rowskip, lB + 2048);
    gA += 32; gB += 32;
    __syncthreads();

    short8 af[4], bf[4];
#pragma unroll
    for (int mi = 0; mi < 4; ++mi)
      af[mi] = *reinterpret_cast<const short8*>(&sA[(wr * 64 + mi * 16 + frow) * 32 + fkb]);
#pragma unroll
    for (int ni = 0; ni < 4; ++ni)
      bf[ni] = *reinterpret_cast<const short8*>(&sB[(wc * 64 + ni * 16 + frow) * 32 + fkb]);
#pragma unroll
    for (int mi = 0; mi < 4; ++mi)
#pragma unroll
      for (int ni = 0; ni < 4; ++ni)
        acc[mi][ni] = __builtin_amdgcn_mfma_f32_16x16x32_bf16(af[mi], bf[ni], acc[mi][ni], 0, 0, 0);
    __syncthreads();
  }

  const int r0 = bm * 128 + wr * 64 + (lane >> 4) * 4;
  const int c0 = bn * 128 + wc * 64 + frow;
#pragma unroll
  for (int mi = 0; mi < 4; ++mi)
#pragma unroll
    for (int ni = 0; ni < 4; ++ni)
#pragma unroll
      for (int j = 0; j < 4; ++j)
        C[(size_t)(r0 + mi * 16 + j) * N + (c0 + ni * 16)] = acc[mi][ni][j];
}

extern "C" void kernel_launch(void* const* d_in, const int* in_sizes, int n_in,
                              void* d_out, int out_size, void* d_ws, size_t ws_size,
                              hipStream_t stream) {
  const float* x      = (const float*)d_in[0];
  const float* gate_w = (const float*)d_in[1];
  const float* up_w   = (const float*)d_in[2];
  const float* down_w = (const float*)d_in[3];
  float* y = (float*)d_out;

  const int Mtok = 4096;  // B*S
  const int H = 2048;
  const int I = 8192;

  // ws layout (bf16 elements): x | gate | up | down | hmid  -> ~184.5 MiB
  unsigned short* x_bf = (unsigned short*)d_ws;
  unsigned short* g_bf = x_bf + (size_t)Mtok * H;
  unsigned short* u_bf = g_bf + (size_t)I * H;
  unsigned short* d_bf = u_bf + (size_t)I * H;
  unsigned short* h_bf = d_bf + (size_t)H * I;

  cvt_f32_bf16<<<2048, 256, 0, stream>>>(x,      x_bf, (Mtok * H) / 4);
  cvt_f32_bf16<<<2048, 256, 0, stream>>>(gate_w, g_bf, (I * H) / 4);
  cvt_f32_bf16<<<2048, 256, 0, stream>>>(up_w,   u_bf, (I * H) / 4);
  cvt_f32_bf16<<<2048, 256, 0, stream>>>(down_w, d_bf, (H * I) / 4);

  dim3 grid1(Mtok / 128, I / 128);
  gemm1_swiglu<<<grid1, 256, 0, stream>>>(x_bf, g_bf, u_bf, h_bf, Mtok, I, H);

  dim3 grid2(Mtok / 128, H / 128);
  gemm2_bt<<<grid2, 256, 0, stream>>>(h_bf, d_bf, y, Mtok, H, I);
}

// Round 2
// 462.002 us; speedup vs baseline: 1.8709x; 1.8709x over previous
//
#include <hip/hip_runtime.h>
#include <hip/hip_bf16.h>
#include <stdint.h>

typedef __attribute__((ext_vector_type(4))) float f32x4;
typedef __attribute__((ext_vector_type(8))) short short8;

__device__ __forceinline__ unsigned short f32_to_bf16_rne(float f) {
  union { float f; unsigned int u; } v; v.f = f;
  unsigned int u = v.u;
  unsigned int r = u + 0x7fffu + ((u >> 16) & 1u);
  return (unsigned short)(r >> 16);
}

#define GLOAD16(gp, lp)                                                 \
  __builtin_amdgcn_global_load_lds(                                     \
      (const __attribute__((address_space(1))) void*)(const void*)(gp), \
      (__attribute__((address_space(3))) void*)(void*)(lp), 16, 0, 0)

#define BAR() __builtin_amdgcn_s_barrier()
#define WAIT_LGKM0() asm volatile("s_waitcnt lgkmcnt(0)" ::: "memory")
#define WAIT_VM4() asm volatile("s_waitcnt vmcnt(4)" ::: "memory")
#define WAIT_VM0() asm volatile("s_waitcnt vmcnt(0)" ::: "memory")

// ---------------- converters / packers ----------------

__global__ __launch_bounds__(256) void cvt_f32_bf16(const float* __restrict__ in,
                                                    unsigned short* __restrict__ out,
                                                    int n4) {
  int i = blockIdx.x * 256 + threadIdx.x;
  int stride = gridDim.x * 256;
  for (; i < n4; i += stride) {
    float4 v = reinterpret_cast<const float4*>(in)[i];
    ushort4 o;
    o.x = f32_to_bf16_rne(v.x);
    o.y = f32_to_bf16_rne(v.y);
    o.z = f32_to_bf16_rne(v.z);
    o.w = f32_to_bf16_rne(v.w);
    reinterpret_cast<ushort4*>(out)[i] = o;
  }
}

// Bcat[16384][2048]: row R -> grp=R>>5, s=R&31; s<16: gate row grp*16+s,
// else up row grp*16+(s-16). 16-row interleave makes gate/up adjacent
// n-fragments inside one wave's MFMA tile.
__global__ __launch_bounds__(256) void pack_gateup(const float* __restrict__ g,
                                                   const float* __restrict__ u,
                                                   unsigned short* __restrict__ out) {
  const int n = 16384 * 512;  // float4 count (H=2048 -> 512 float4/row)
  int idx = blockIdx.x * 256 + threadIdx.x;
  for (; idx < n; idx += gridDim.x * 256) {
    int R = idx >> 9, h4 = idx & 511;
    int grp = R >> 5, s = R & 31;
    const float* src = (s < 16 ? g : u) + (((size_t)(grp * 16 + (s & 15))) << 11) + (h4 << 2);
    float4 v = *reinterpret_cast<const float4*>(src);
    ushort4 o;
    o.x = f32_to_bf16_rne(v.x);
    o.y = f32_to_bf16_rne(v.y);
    o.z = f32_to_bf16_rne(v.z);
    o.w = f32_to_bf16_rne(v.w);
    *reinterpret_cast<ushort4*>(out + ((size_t)idx << 2)) = o;
  }
}

__global__ __launch_bounds__(256) void reduce_add(const float* __restrict__ a,
                                                  const float* __restrict__ b,
                                                  float* __restrict__ o, int n4) {
  int i = blockIdx.x * 256 + threadIdx.x;
  for (; i < n4; i += gridDim.x * 256) {
    float4 x = reinterpret_cast<const float4*>(a)[i];
    float4 y = reinterpret_cast<const float4*>(b)[i];
    float4 z;
    z.x = x.x + y.x; z.y = x.y + y.y; z.z = x.z + y.z; z.w = x.w + y.w;
    reinterpret_cast<float4*>(o)[i] = z;
  }
}

// ---------------- 256x256x64 8-phase GEMM ----------------
// C = A(M x K) * B(N x K)^T, both bf16 row-major (K-major).
// 8 waves (512 thr), wave tile 128x64 (WARPS_M=2 x WARPS_N=4).
// LDS 128 KiB: A,B each 2dbuf x 2half x [128][64] bf16.
// Swizzle: logical byte off ^= ((row&7)<<4); applied on the global SOURCE of
// global_load_lds (dest linear) and on ds_read addresses (involution).
// EPI=0: plain fp32 C (split-K partial, offset blockIdx.z*zstride)
// EPI=1: swiglu epilogue over (gate,up) fragment pairs -> bf16 Hm, N_hm=Nout.

#define MFMA_Q(MH, NH)                                                        \
  do {                                                                        \
    _Pragma("unroll") for (int kh = 0; kh < 2; ++kh) {                        \
      _Pragma("unroll") for (int mi = 0; mi < 4; ++mi) {                      \
        _Pragma("unroll") for (int ni = 0; ni < 2; ++ni) {                    \
          acc[(MH)*4 + mi][(NH)*2 + ni] =                                     \
              __builtin_amdgcn_mfma_f32_16x16x32_bf16(                        \
                  a[mi][kh], b[(NH)*2 + ni][kh],                              \
                  acc[(MH)*4 + mi][(NH)*2 + ni], 0, 0, 0);                    \
        }                                                                     \
      }                                                                       \
    }                                                                         \
  } while (0)

#define STAGE(MAT, BUF, H, T)                                                       \
  do {                                                                              \
    const unsigned short* p0_ =                                                     \
        MAT##base + (size_t)((H)*128 + r0) * ld##MAT + (size_t)(T)*64 + c0;         \
    const unsigned short* p1_ =                                                     \
        MAT##base + (size_t)((H)*128 + r1) * ld##MAT + (size_t)(T)*64 + c1;         \
    GLOAD16(p0_, &s##MAT[BUF][H][off0 >> 1]);                                       \
    GLOAD16(p1_, &s##MAT[BUF][H][(off0 >> 1) + 512]);                               \
  } while (0)

#define LDA(dst, BUF, MI, KH)                                                 \
  {                                                                           \
    int lb_ = ((MI)*16 + frow) * 128 + (KH)*64 + kg * 16;                     \
    int ph_ = lb_ ^ ((frow & 7) << 4);                                        \
    dst = *reinterpret_cast<const short8*>(                                   \
        reinterpret_cast<const char*>(&sA[BUF][wr][0]) + ph_);                \
  }

#define LDB(dst, BUF, NI, KH)                                                 \
  {                                                                           \
    int lb_ = ((wc & 1) * 64 + (NI)*16 + frow) * 128 + (KH)*64 + kg * 16;     \
    int ph_ = lb_ ^ ((frow & 7) << 4);                                        \
    dst = *reinterpret_cast<const short8*>(                                   \
        reinterpret_cast<const char*>(&sB[BUF][wc >> 1][0]) + ph_);           \
  }

template <int EPI>
__global__ __launch_bounds__(512, 2) void gemm8p(
    const unsigned short* __restrict__ A, const unsigned short* __restrict__ B,
    void* __restrict__ Cout, int K, int ldA, int ldB, int Nout, size_t zstride) {
  __shared__ unsigned short sA[2][2][128 * 64];
  __shared__ unsigned short sB[2][2][128 * 64];

  const int t = threadIdx.x;
  const int wv = t >> 6, ln = t & 63;
  const int wr = wv >> 2, wc = wv & 3;
  const int frow = ln & 15, kg = ln >> 4;
  const int bm = blockIdx.x, bn = blockIdx.y;

  A += (size_t)blockIdx.z * K;  // split-K offset along the K-major rows
  B += (size_t)blockIdx.z * K;

  // staging precompute: linear LDS byte offsets (wave-uniform base + lane*16),
  // then swizzled logical coords -> pre-swizzled global source.
  const int off0 = wv * 2048 + ln * 16;
  const int off1 = off0 + 1024;
  const int s0 = off0 ^ (((off0 >> 7) & 7) << 4);
  const int s1 = off1 ^ (((off1 >> 7) & 7) << 4);
  const int r0 = s0 >> 7, c0 = (s0 & 127) >> 1;
  const int r1 = s1 >> 7, c1 = (s1 & 127) >> 1;

  const unsigned short* Abase = A + (size_t)(bm * 256) * ldA;
  const unsigned short* Bbase = B + (size_t)(bn * 256) * ldB;

  f32x4 acc[8][4] = {};
  short8 a[4][2], b[4][2];

  const int NT = K >> 6;  // K / 64, NT >= 2

  // Prologue: tile0 fully, tile1 {B.h0, A.h0}. vmcnt(4) allows the last 2
  // halves (4 loads) to stay in flight.
  STAGE(A, 0, 0, 0); STAGE(A, 0, 1, 0);
  STAGE(B, 0, 0, 0); STAGE(B, 0, 1, 0);
  STAGE(B, 1, 0, 1); STAGE(A, 1, 0, 1);
  WAIT_VM4();
  BAR();

  for (int tt = 0; tt < NT; ++tt) {
    const int buf = tt & 1, nbuf = buf ^ 1;
    // Phase 0: read a(m-lo), b(n-lo); stage B.h1(tt+1)
#pragma unroll
    for (int mi = 0; mi < 4; ++mi) { LDA(a[mi][0], buf, mi, 0); LDA(a[mi][1], buf, mi, 1); }
#pragma unroll
    for (int ni = 0; ni < 2; ++ni) { LDB(b[ni][0], buf, ni, 0); LDB(b[ni][1], buf, ni, 1); }
    if (tt + 1 < NT) STAGE(B, nbuf, 1, tt + 1);
    BAR(); WAIT_LGKM0();
    __builtin_amdgcn_s_setprio(1); MFMA_Q(0, 0); __builtin_amdgcn_s_setprio(0);
    BAR();
    // Phase 1: read b(n-hi); stage A.h1(tt+1)
#pragma unroll
    for (int ni = 2; ni < 4; ++ni) { LDB(b[ni][0], buf, ni, 0); LDB(b[ni][1], buf, ni, 1); }
    if (tt + 1 < NT) STAGE(A, nbuf, 1, tt + 1);
    BAR(); WAIT_LGKM0();
    __builtin_amdgcn_s_setprio(1); MFMA_Q(0, 1); __builtin_amdgcn_s_setprio(0);
    BAR();
    // Phase 2: read a(m-hi); stage B.h0(tt+2)  (B reads of this buf done @ph1)
#pragma unroll
    for (int mi = 0; mi < 4; ++mi) { LDA(a[mi][0], buf, mi + 4, 0); LDA(a[mi][1], buf, mi + 4, 1); }
    if (tt + 2 < NT) STAGE(B, buf, 0, tt + 2);
    BAR(); WAIT_LGKM0();
    __builtin_amdgcn_s_setprio(1); MFMA_Q(1, 0); __builtin_amdgcn_s_setprio(0);
    BAR();
    // Phase 3: stage A.h0(tt+2) (A reads of this buf done @ph2); group-end wait
    if (tt + 2 < NT) STAGE(A, buf, 0, tt + 2);
    BAR(); WAIT_LGKM0();
    __builtin_amdgcn_s_setprio(1); MFMA_Q(1, 1); __builtin_amdgcn_s_setprio(0);
    if (tt < NT - 1) {
      if (tt + 2 < NT) { WAIT_VM4(); } else { WAIT_VM0(); }
    }
    BAR();
  }

  // ---------------- epilogue ----------------
  if (EPI == 0) {
    float* C = reinterpret_cast<float*>(Cout) + (size_t)blockIdx.z * zstride;
    const int rb = bm * 256 + wr * 128 + kg * 4;
    const int cb = bn * 256 + wc * 64 + frow;
#pragma unroll
    for (int mi = 0; mi < 8; ++mi)
#pragma unroll
      for (int ni = 0; ni < 4; ++ni)
#pragma unroll
        for (int j = 0; j < 4; ++j)
          C[(size_t)(rb + mi * 16 + j) * Nout + (cb + ni * 16)] = acc[mi][ni][j];
  } else {
    // fragment pairs (2p, 2p+1) = (gate, up) for Hm col block p
    unsigned short* Hm = reinterpret_cast<unsigned short*>(Cout);
    const int rb = bm * 256 + wr * 128 + kg * 4;
    const int cb = bn * 128 + wc * 32 + frow;
#pragma unroll
    for (int mi = 0; mi < 8; ++mi)
#pragma unroll
      for (int p = 0; p < 2; ++p)
#pragma unroll
        for (int j = 0; j < 4; ++j) {
          float g = acc[mi][2 * p][j];
          float u = acc[mi][2 * p + 1][j];
          float h = g * u / (1.0f + __expf(-g));
          Hm[(size_t)(rb + mi * 16 + j) * Nout + (cb + p * 16)] = f32_to_bf16_rne(h);
        }
  }
}

// ---------------- host ----------------

extern "C" void kernel_launch(void* const* d_in, const int* in_sizes, int n_in,
                              void* d_out, int out_size, void* d_ws, size_t ws_size,
                              hipStream_t stream) {
  const float* x      = (const float*)d_in[0];
  const float* gate_w = (const float*)d_in[1];
  const float* up_w   = (const float*)d_in[2];
  const float* down_w = (const float*)d_in[3];
  float* y = (float*)d_out;

  const int Mtok = 4096, H = 2048, I = 8192;

  // ws layout (bytes): x_bf 16M | Bcat 64M | d_bf 32M | h_bf 64M  (176 MiB)
  unsigned short* x_bf = (unsigned short*)d_ws;
  unsigned short* Bcat = x_bf + (size_t)Mtok * H;
  unsigned short* d_bf = Bcat + (size_t)2 * I * H;
  unsigned short* h_bf = d_bf + (size_t)H * I;
  // split-K partials reuse the Bcat region after gemm1 is done (2 x 32 MB)
  float* part = (float*)Bcat;

  cvt_f32_bf16<<<2048, 256, 0, stream>>>(x, x_bf, (Mtok * H) / 4);
  pack_gateup<<<2048, 256, 0, stream>>>(gate_w, up_w, Bcat);
  cvt_f32_bf16<<<2048, 256, 0, stream>>>(down_w, d_bf, (H * I) / 4);

  // gemm1: (4096 x 2048) * (16384 x 2048)^T -> swiglu -> h_bf (4096 x 8192)
  gemm8p<1><<<dim3(Mtok / 256, (2 * I) / 256, 1), 512, 0, stream>>>(
      x_bf, Bcat, h_bf, H, H, H, I, 0);

  // gemm2: split-K=2: (4096 x 8192) * (2048 x 8192)^T -> partials
  gemm8p<0><<<dim3(Mtok / 256, H / 256, 2), 512, 0, stream>>>(
      h_bf, d_bf, part, I / 2, I, I, H, (size_t)Mtok * H);

  reduce_add<<<2048, 256, 0, stream>>>(part, part + (size_t)Mtok * H, y,
                                       (Mtok * H) / 4);
}